// Round 9
// baseline (283.551 us; speedup 1.0000x reference)
//
#include <hip/hip_runtime.h>
#include <hip/hip_bf16.h>

// Swin block fully fused, bf16 MFMA. B=64, H=W=56, C=96, nh=3, d=32, WS=7, SS=3, N=49, nW=64.
// Round 9: round-8 single-x-read + round-7 register repack (Q/AO/yn/h never touch LDS)
// -> LDS 39.4 KB -> 4 blocks/CU; sigmoid GELU.
typedef __attribute__((ext_vector_type(8))) short short8;  // 8 bf16 = one A/B frag
typedef __attribute__((ext_vector_type(4))) float f32x4;   // C/D frag

constexpr int HW = 56;

// ---- LDS pool (bf16 elements). Frag-read bases 16B-aligned. ----
constexpr int SR    = 104;             // row stride for [64][96] token-major buffers
constexpr int SVT   = 200;             // row stride for vT [32][3*64]
constexpr int OFF_X = 0;               // [64][SR]: xln -> P (own row, stage 3)
constexpr int OFF_K = 64 * SR;         // [64][SR]: k (never overwritten)
constexpr int OFF_V = 2 * 64 * SR;     // [32][SVT]: v^T (row d&31, col (d>>5)*64+tok)
constexpr int POOLN = OFF_V + 32 * SVT;  // 19712 shorts = 39424 B -> 4 blocks/CU

// ---- d_ws layout (bf16), frag-major: [(tile*3+s)*512 + lane*8 + j] ----
constexpr int WQKV  = 0;               // 18 tiles
constexpr int WPROJ = 27648;           // 6 tiles
constexpr int WFC1  = 36864;           // 24 tiles (tile = 6*cn + nt)
constexpr int WFC2  = 73728;           // 24 tiles (tile = nt*4 + cn)
constexpr int WTOT  = 110592;          // *2B = 221184 bytes

__device__ __forceinline__ ushort bfc(float f) {
  union { __hip_bfloat16 h; ushort u; } v;
  v.h = __float2bfloat16(f);
  return v.u;
}
__device__ __forceinline__ uint pk2(float a, float b) {
  union { __hip_bfloat162 h2; uint u; } v;
  v.h2 = __float22bfloat162_rn(make_float2(a, b));
  return v.u;
}
__device__ __forceinline__ void st4(short* p, float a, float b, float c, float d) {
  uint2 u; u.x = pk2(a, b); u.y = pk2(c, d);
  *(uint2*)p = u;
}
__device__ __forceinline__ short8 ldw8(const float* p) {
  float4 a = *(const float4*)p;
  float4 b = *(const float4*)(p + 4);
  short8 r;
  r[0] = (short)bfc(a.x); r[1] = (short)bfc(a.y); r[2] = (short)bfc(a.z); r[3] = (short)bfc(a.w);
  r[4] = (short)bfc(b.x); r[5] = (short)bfc(b.y); r[6] = (short)bfc(b.z); r[7] = (short)bfc(b.w);
  return r;
}
template<bool PRE>
__device__ __forceinline__ short8 wfrag(const short* wsb, int ts, int lane, const float* fsrc) {
  if constexpr (PRE) return *(const short8*)&wsb[(ts << 9) + lane * 8];
  else               return ldw8(fsrc);
}
// GELU sigmoid form: x * sigma(1.702 x).  ~5 VALU ops; |err| <= ~0.01 abs, fine vs 0.109 thr.
__device__ __forceinline__ float gelu(float v) {
  return v / (1.0f + __expf(-1.702f * v));
}
// Thread holds 4-chan chunks A (chans 32s+4gq..+3) and B (chans 32s+16+4gq..+3) of
// its own token.  Returns the B-frag covering chans 32s+8gq+{0..7} of the same token.
__device__ __forceinline__ short8 repack(f32x4 A, f32x4 B, int ln, int gq) {
  uint a_lo = pk2(A[0], A[1]), a_hi = pk2(A[2], A[3]);
  uint b_lo = pk2(B[0], B[1]), b_hi = pk2(B[2], B[3]);
  int s0 = ln + (((2 * gq)     & 3) << 4);
  int s1 = ln + (((2 * gq + 1) & 3) << 4);
  uint A0 = __shfl(a_lo, s0, 64), B0 = __shfl(b_lo, s0, 64);
  uint A1 = __shfl(a_hi, s0, 64), B1 = __shfl(b_hi, s0, 64);
  uint A2 = __shfl(a_lo, s1, 64), B2 = __shfl(b_lo, s1, 64);
  uint A3 = __shfl(a_hi, s1, 64), B3 = __shfl(b_hi, s1, 64);
  bool uA = (gq < 2);
  union { uint u[4]; short8 s8; } r;
  r.u[0] = uA ? A0 : B0; r.u[1] = uA ? A1 : B1;
  r.u[2] = uA ? A2 : B2; r.u[3] = uA ? A3 : B3;
  return r.s8;
}

// one-shot weight conversion f32 -> bf16, frag-major
__global__ __launch_bounds__(256) void cvt_weights(
    const float* __restrict__ qkv_w, const float* __restrict__ proj_w,
    const float* __restrict__ fc1_w, const float* __restrict__ fc2_w,
    short* __restrict__ ws)
{
  int idx = blockIdx.x * 256 + threadIdx.x;
  if (idx >= WTOT) return;
  int j = idx & 7, lane = (idx >> 3) & 63;
  int cl = lane & 15;
  int g  = 8 * (lane >> 4) + j;
  float v;
  if (idx < WPROJ) {
    int ts = idx >> 9; int tile = ts / 3, s = ts - 3 * tile;
    v = qkv_w[(size_t)(16 * tile + cl) * 96 + 32 * s + g];
  } else if (idx < WFC1) {
    int ts = (idx - WPROJ) >> 9; int tile = ts / 3, s = ts - 3 * tile;
    v = proj_w[(size_t)(16 * tile + cl) * 96 + 32 * s + g];
  } else if (idx < WFC2) {
    int ts = (idx - WFC1) >> 9; int tile = ts / 3, s = ts - 3 * tile;
    v = fc1_w[(size_t)(16 * tile + cl) * 96 + 32 * s + g];
  } else {
    int ts = (idx - WFC2) >> 9; int T = ts / 3, s = ts - 3 * T;
    int nt = T >> 2, cn = T & 3;
    v = fc2_w[(size_t)(16 * nt + cl) * 384 + 96 * cn + 32 * s + g];
  }
  ws[idx] = (short)bfc(v);
}

template<bool PRE>
__global__ __launch_bounds__(256, 4) void swin_mfma_kernel(
    const float* __restrict__ x,          // [B,3136,96]
    const float* __restrict__ attn_mask,  // [64,49,49]
    const int*   __restrict__ rel_index,  // [2401]
    const float* __restrict__ n1g, const float* __restrict__ n1b,
    const float* __restrict__ qkv_w, const float* __restrict__ qkv_b,
    const float* __restrict__ rel_tab,    // [169,3]
    const float* __restrict__ proj_w, const float* __restrict__ proj_b,
    const float* __restrict__ n2g, const float* __restrict__ n2b,
    const float* __restrict__ fc1_w, const float* __restrict__ fc1_b,
    const float* __restrict__ fc2_w, const float* __restrict__ fc2_b,
    const short* __restrict__ wsw,
    float* __restrict__ out)              // [B,3136,96]
{
  __shared__ alignas(16) short pool[POOLN];

  const int tid  = threadIdx.x;
  const int wv   = tid >> 6;          // wave id = token 16-strip owner
  const int lane = tid & 63;
  const int ln   = lane & 15;
  const int gq   = lane >> 4;
  const int bw   = blockIdx.x;
  const int b    = bw >> 6, widx = bw & 63;
  const int wr   = widx >> 3, wc = widx & 7;

  const f32x4 zf = {0.f, 0.f, 0.f, 0.f};
  const int qq = 16 * wv + ln;        // this thread's token row

  auto gbase = [&](int n) -> size_t {
    int i = n / 7, j = n - 7 * i;
    int h = wr * 7 + i + 3; if (h >= HW) h -= HW;   // roll(-3)
    int w = wc * 7 + j + 3; if (w >= HW) w -= HW;
    return ((size_t)b * (HW * HW) + (size_t)h * HW + w) * 96;
  };
  const size_t obase = gbase(qq < 49 ? qq : 48);

  // ---- stage 1: token-per-thread-column load + LN1 -> xln; raw x kept in VGPRs ----
  float xraw[6][4];
  {
    if (qq < 49) {
      const float* xr = x + obase;
      #pragma unroll
      for (int nt = 0; nt < 6; ++nt) {
        float4 v = *(const float4*)&xr[16 * nt + 4 * gq];
        xraw[nt][0] = v.x; xraw[nt][1] = v.y; xraw[nt][2] = v.z; xraw[nt][3] = v.w;
      }
    } else {
      #pragma unroll
      for (int nt = 0; nt < 6; ++nt)
        xraw[nt][0] = xraw[nt][1] = xraw[nt][2] = xraw[nt][3] = 0.f;
    }
    float s1 = 0.f, s2 = 0.f;
    #pragma unroll
    for (int nt = 0; nt < 6; ++nt)
      #pragma unroll
      for (int r = 0; r < 4; ++r) { s1 += xraw[nt][r]; s2 += xraw[nt][r] * xraw[nt][r]; }
    s1 += __shfl_xor(s1, 16, 64); s1 += __shfl_xor(s1, 32, 64);
    s2 += __shfl_xor(s2, 16, 64); s2 += __shfl_xor(s2, 32, 64);
    float mean = s1 * (1.f / 96.f);
    float inv  = rsqrtf(s2 * (1.f / 96.f) - mean * mean + 1e-5f);
    #pragma unroll
    for (int nt = 0; nt < 6; ++nt) {
      float4 g4 = *(const float4*)&n1g[16 * nt + 4 * gq];
      float4 b4 = *(const float4*)&n1b[16 * nt + 4 * gq];
      st4(&pool[OFF_X + qq * SR + 16 * nt + 4 * gq],
          (xraw[nt][0] - mean) * inv * g4.x + b4.x,
          (xraw[nt][1] - mean) * inv * g4.y + b4.y,
          (xraw[nt][2] - mean) * inv * g4.z + b4.z,
          (xraw[nt][3] - mean) * inv * g4.w + b4.w);
    }
  }
  __syncthreads();

  // ---- stage 2a: A-frags from xln ----
  short8 af[3][4];
  #pragma unroll
  for (int s = 0; s < 3; ++s)
    #pragma unroll
    for (int m = 0; m < 4; ++m)
      af[s][m] = *(const short8*)&pool[OFF_X + (16 * m + ln) * SR + 32 * s + 8 * gq];
  short8 aq[3];   // own-row A-frag
  #pragma unroll
  for (int s = 0; s < 3; ++s)
    aq[s] = *(const short8*)&pool[OFF_X + qq * SR + 32 * s + 8 * gq];

  // ---- stage 2b: K/V production, N-split across waves (3 tiles each) ----
  for (int t = 6 + wv; t < 18; t += 4) {
    short8 wf[3];
    #pragma unroll
    for (int s = 0; s < 3; ++s)
      wf[s] = wfrag<PRE>(wsw + WQKV, t * 3 + s, lane,
                         qkv_w + (size_t)(16 * t + ln) * 96 + 32 * s + 8 * gq);
    if (t < 12) {
      // K: D[chan][tok], chan = 16(t-6)+4gq+r, tok = 16m+ln
      float4 b4 = *(const float4*)&qkv_b[16 * t + 4 * gq];
      #pragma unroll
      for (int m = 0; m < 4; ++m) {
        f32x4 acc = zf;
        #pragma unroll
        for (int s = 0; s < 3; ++s)
          acc = __builtin_amdgcn_mfma_f32_16x16x32_bf16(wf[s], af[s][m], acc, 0, 0, 0);
        int tok = 16 * m + ln;
        st4(&pool[OFF_K + tok * SR + 16 * (t - 6) + 4 * gq],
            acc[0] + b4.x, acc[1] + b4.y, acc[2] + b4.z, acc[3] + b4.w);
      }
    } else {
      // V: D[tok][chan] -> store transposed V^T[d][h*64+tok]
      int d  = 16 * (t - 12) + ln;
      float bv = qkv_b[192 + d];
      int dd = d & 31, hh = d >> 5;
      #pragma unroll
      for (int m = 0; m < 4; ++m) {
        f32x4 acc = zf;
        #pragma unroll
        for (int s = 0; s < 3; ++s)
          acc = __builtin_amdgcn_mfma_f32_16x16x32_bf16(af[s][m], wf[s], acc, 0, 0, 0);
        st4(&pool[OFF_V + dd * SVT + hh * 64 + 16 * m + 4 * gq],
            acc[0] + bv, acc[1] + bv, acc[2] + bv, acc[3] + bv);
      }
    }
  }

  // ---- stage 2c: Q production, M-split (own token), straight to registers ----
  short8 bq[3];
  {
    const float qsc = 0.17677669529663687f;
    #pragma unroll
    for (int h = 0; h < 3; ++h) {
      f32x4 qa = zf, qb = zf;
      #pragma unroll
      for (int s = 0; s < 3; ++s) {
        qa = __builtin_amdgcn_mfma_f32_16x16x32_bf16(
            wfrag<PRE>(wsw + WQKV, (2 * h) * 3 + s, lane,
                       qkv_w + (size_t)(16 * (2 * h) + ln) * 96 + 32 * s + 8 * gq),
            aq[s], qa, 0, 0, 0);
        qb = __builtin_amdgcn_mfma_f32_16x16x32_bf16(
            wfrag<PRE>(wsw + WQKV, (2 * h + 1) * 3 + s, lane,
                       qkv_w + (size_t)(16 * (2 * h + 1) + ln) * 96 + 32 * s + 8 * gq),
            aq[s], qb, 0, 0, 0);
      }
      float4 ba = *(const float4*)&qkv_b[16 * (2 * h) + 4 * gq];
      float4 bb = *(const float4*)&qkv_b[16 * (2 * h + 1) + 4 * gq];
      f32x4 QA, QB;
      QA[0] = (qa[0] + ba.x) * qsc; QA[1] = (qa[1] + ba.y) * qsc;
      QA[2] = (qa[2] + ba.z) * qsc; QA[3] = (qa[3] + ba.w) * qsc;
      QB[0] = (qb[0] + bb.x) * qsc; QB[1] = (qb[1] + bb.y) * qsc;
      QB[2] = (qb[2] + bb.z) * qsc; QB[3] = (qb[3] + bb.w) * qsc;
      bq[h] = repack(QA, QB, ln, gq);
    }
  }
  __syncthreads();
  // From here on: every LDS write is to this wave's own token rows -> no more barriers.

  // ---- stage 3: attention ----
  int   relvv[4][4];
  float maskb[4][4];
  {
    int qc = qq < 49 ? qq : 48;
    #pragma unroll
    for (int nt = 0; nt < 4; ++nt)
      #pragma unroll
      for (int r = 0; r < 4; ++r) {
        int key = 16 * nt + 4 * gq + r;
        if (key < 49) {
          int qk = qc * 49 + key;
          relvv[nt][r] = rel_index[qk];
          maskb[nt][r] = attn_mask[(size_t)widx * 2401 + qk];
        } else {
          relvv[nt][r] = 0;
          maskb[nt][r] = -1e30f;
        }
      }
  }

  f32x4 aoA[3], aoB[3];   // attn-out chans {0..15},{16..31}(+4gq+r) per head, token qq
  #pragma unroll
  for (int h = 0; h < 3; ++h) {
    f32x4 sc[4];
    #pragma unroll
    for (int nt = 0; nt < 4; ++nt) {
      short8 ak = *(const short8*)&pool[OFF_K + (16 * nt + ln) * SR + h * 32 + 8 * gq];
      sc[nt] = __builtin_amdgcn_mfma_f32_16x16x32_bf16(ak, bq[h], zf, 0, 0, 0);
    }
    float pv[4][4];
    float mx = -1e30f;
    #pragma unroll
    for (int nt = 0; nt < 4; ++nt)
      #pragma unroll
      for (int r = 0; r < 4; ++r) {
        float v = sc[nt][r] + rel_tab[relvv[nt][r] * 3 + h] + maskb[nt][r];
        pv[nt][r] = v;
        mx = fmaxf(mx, v);
      }
    mx = fmaxf(mx, __shfl_xor(mx, 16, 64));
    mx = fmaxf(mx, __shfl_xor(mx, 32, 64));
    float sum = 0.f;
    #pragma unroll
    for (int nt = 0; nt < 4; ++nt)
      #pragma unroll
      for (int r = 0; r < 4; ++r) { pv[nt][r] = __expf(pv[nt][r] - mx); sum += pv[nt][r]; }
    sum += __shfl_xor(sum, 16, 64);
    sum += __shfl_xor(sum, 32, 64);
    float inv = 1.f / sum;
    // P -> own X row (xln dead after stage 2)
    #pragma unroll
    for (int nt = 0; nt < 4; ++nt)
      st4(&pool[OFF_X + qq * SR + 16 * nt + 4 * gq],
          pv[nt][0] * inv, pv[nt][1] * inv, pv[nt][2] * inv, pv[nt][3] * inv);

    // PV: D[d][q] = V^T-rows x P-rows; result stays in registers
    short8 bp0 = *(const short8*)&pool[OFF_X + qq * SR + 8 * gq];
    short8 bp1 = *(const short8*)&pool[OFF_X + qq * SR + 32 + 8 * gq];
    {
      short8 av0 = *(const short8*)&pool[OFF_V + ln * SVT + h * 64 + 8 * gq];
      short8 av1 = *(const short8*)&pool[OFF_V + ln * SVT + h * 64 + 32 + 8 * gq];
      f32x4 o = __builtin_amdgcn_mfma_f32_16x16x32_bf16(av0, bp0, zf, 0, 0, 0);
      o = __builtin_amdgcn_mfma_f32_16x16x32_bf16(av1, bp1, o, 0, 0, 0);
      aoA[h] = o;
    }
    {
      short8 av0 = *(const short8*)&pool[OFF_V + (16 + ln) * SVT + h * 64 + 8 * gq];
      short8 av1 = *(const short8*)&pool[OFF_V + (16 + ln) * SVT + h * 64 + 32 + 8 * gq];
      f32x4 o = __builtin_amdgcn_mfma_f32_16x16x32_bf16(av0, bp0, zf, 0, 0, 0);
      o = __builtin_amdgcn_mfma_f32_16x16x32_bf16(av1, bp1, o, 0, 0, 0);
      aoB[h] = o;
    }
  }

  // ---- stage 4: proj + residual (VGPR) + LN2, all registers ----
  short8 ao8[3];
  #pragma unroll
  for (int s = 0; s < 3; ++s) ao8[s] = repack(aoA[s], aoB[s], ln, gq);

  float y[6][4];
  #pragma unroll
  for (int nt = 0; nt < 6; ++nt) {
    f32x4 acc = zf;
    #pragma unroll
    for (int s = 0; s < 3; ++s)
      acc = __builtin_amdgcn_mfma_f32_16x16x32_bf16(
          wfrag<PRE>(wsw + WPROJ, nt * 3 + s, lane,
                     proj_w + (size_t)(16 * nt + ln) * 96 + 32 * s + 8 * gq),
          ao8[s], acc, 0, 0, 0);
    float4 pb = *(const float4*)&proj_b[16 * nt + 4 * gq];
    y[nt][0] = acc[0] + pb.x + xraw[nt][0];
    y[nt][1] = acc[1] + pb.y + xraw[nt][1];
    y[nt][2] = acc[2] + pb.z + xraw[nt][2];
    y[nt][3] = acc[3] + pb.w + xraw[nt][3];
  }
  float s1 = 0.f, s2 = 0.f;
  #pragma unroll
  for (int nt = 0; nt < 6; ++nt)
    #pragma unroll
    for (int r = 0; r < 4; ++r) { s1 += y[nt][r]; s2 += y[nt][r] * y[nt][r]; }
  s1 += __shfl_xor(s1, 16, 64); s1 += __shfl_xor(s1, 32, 64);
  s2 += __shfl_xor(s2, 16, 64); s2 += __shfl_xor(s2, 32, 64);
  float mean = s1 * (1.f / 96.f);
  float linv = rsqrtf(s2 * (1.f / 96.f) - mean * mean + 1e-5f);

  short8 yq[3];
  #pragma unroll
  for (int s = 0; s < 3; ++s) {
    float4 gA = *(const float4*)&n2g[16 * (2 * s) + 4 * gq];
    float4 bA = *(const float4*)&n2b[16 * (2 * s) + 4 * gq];
    float4 gB = *(const float4*)&n2g[16 * (2 * s + 1) + 4 * gq];
    float4 bB = *(const float4*)&n2b[16 * (2 * s + 1) + 4 * gq];
    f32x4 YA, YB;
    YA[0] = (y[2 * s][0] - mean) * linv * gA.x + bA.x;
    YA[1] = (y[2 * s][1] - mean) * linv * gA.y + bA.y;
    YA[2] = (y[2 * s][2] - mean) * linv * gA.z + bA.z;
    YA[3] = (y[2 * s][3] - mean) * linv * gA.w + bA.w;
    YB[0] = (y[2 * s + 1][0] - mean) * linv * gB.x + bB.x;
    YB[1] = (y[2 * s + 1][1] - mean) * linv * gB.y + bB.y;
    YB[2] = (y[2 * s + 1][2] - mean) * linv * gB.z + bB.z;
    YB[3] = (y[2 * s + 1][3] - mean) * linv * gB.w + bB.w;
    yq[s] = repack(YA, YB, ln, gq);
  }

  // ---- stage 5: MLP, 4 chunks of 96 hidden, fully register-resident ----
  f32x4 accO[6] = {zf, zf, zf, zf, zf, zf};
  for (int cn = 0; cn < 4; ++cn) {
    f32x4 ha[6];
    #pragma unroll
    for (int nt = 0; nt < 6; ++nt) {
      f32x4 acc = zf;
      #pragma unroll
      for (int s = 0; s < 3; ++s)
        acc = __builtin_amdgcn_mfma_f32_16x16x32_bf16(
            wfrag<PRE>(wsw + WFC1, (6 * cn + nt) * 3 + s, lane,
                       fc1_w + (size_t)(96 * cn + 16 * nt + ln) * 96 + 32 * s + 8 * gq),
            yq[s], acc, 0, 0, 0);
      float4 b1 = *(const float4*)&fc1_b[96 * cn + 16 * nt + 4 * gq];
      ha[nt][0] = gelu(acc[0] + b1.x);
      ha[nt][1] = gelu(acc[1] + b1.y);
      ha[nt][2] = gelu(acc[2] + b1.z);
      ha[nt][3] = gelu(acc[3] + b1.w);
    }
    short8 hq[3];
    #pragma unroll
    for (int s = 0; s < 3; ++s) hq[s] = repack(ha[2 * s], ha[2 * s + 1], ln, gq);
    #pragma unroll
    for (int nt = 0; nt < 6; ++nt) {
      #pragma unroll
      for (int s = 0; s < 3; ++s)
        accO[nt] = __builtin_amdgcn_mfma_f32_16x16x32_bf16(
            wfrag<PRE>(wsw + WFC2, (nt * 4 + cn) * 3 + s, lane,
                       fc2_w + (size_t)(16 * nt + ln) * 384 + 96 * cn + 32 * s + 8 * gq),
            hq[s], accO[nt], 0, 0, 0);
    }
  }

  // ---- stage 6: out = y + mlp + fc2_b (float4 stores) ----
  if (qq < 49) {
    float* dst = out + obase;
    #pragma unroll
    for (int nt = 0; nt < 6; ++nt) {
      float4 fb = *(const float4*)&fc2_b[16 * nt + 4 * gq];
      float4 v;
      v.x = y[nt][0] + accO[nt][0] + fb.x;
      v.y = y[nt][1] + accO[nt][1] + fb.y;
      v.z = y[nt][2] + accO[nt][2] + fb.z;
      v.w = y[nt][3] + accO[nt][3] + fb.w;
      *(float4*)&dst[16 * nt + 4 * gq] = v;
    }
  }
}

extern "C" void kernel_launch(void* const* d_in, const int* in_sizes, int n_in,
                              void* d_out, int out_size, void* d_ws, size_t ws_size,
                              hipStream_t stream) {
  const float* x         = (const float*)d_in[0];
  const float* attn_mask = (const float*)d_in[1];
  const int*   rel_index = (const int*)  d_in[2];
  const float* n1g       = (const float*)d_in[3];
  const float* n1b       = (const float*)d_in[4];
  const float* qkv_w     = (const float*)d_in[5];
  const float* qkv_b     = (const float*)d_in[6];
  const float* rel_tab   = (const float*)d_in[7];
  const float* proj_w    = (const float*)d_in[8];
  const float* proj_b    = (const float*)d_in[9];
  const float* n2g       = (const float*)d_in[10];
  const float* n2b       = (const float*)d_in[11];
  const float* fc1_w     = (const float*)d_in[12];
  const float* fc1_b     = (const float*)d_in[13];
  const float* fc2_w     = (const float*)d_in[14];
  const float* fc2_b     = (const float*)d_in[15];
  float* out = (float*)d_out;

  const int B = in_sizes[0] / (HW * HW * 96);
  const bool pre = ws_size >= (size_t)WTOT * 2;

  if (pre) {
    short* ws = (short*)d_ws;
    cvt_weights<<<(WTOT + 255) / 256, 256, 0, stream>>>(qkv_w, proj_w, fc1_w, fc2_w, ws);
    swin_mfma_kernel<true><<<B * 64, 256, 0, stream>>>(
        x, attn_mask, rel_index, n1g, n1b, qkv_w, qkv_b, rel_tab, proj_w, proj_b,
        n2g, n2b, fc1_w, fc1_b, fc2_w, fc2_b, (const short*)ws, out);
  } else {
    swin_mfma_kernel<false><<<B * 64, 256, 0, stream>>>(
        x, attn_mask, rel_index, n1g, n1b, qkv_w, qkv_b, rel_tab, proj_w, proj_b,
        n2g, n2b, fc1_w, fc1_b, fc2_w, fc2_b, (const short*)nullptr, out);
  }
}

// Round 10
// 183.098 us; speedup vs baseline: 1.5486x; 1.5486x over previous
//
#include <hip/hip_runtime.h>
#include <hip/hip_bf16.h>

// Swin block fully fused, bf16 MFMA. B=64, H=W=56, C=96, nh=3, d=32, WS=7, SS=3, N=49, nW=64.
// Round 10: round-8 base + cooperative weight staging (global_load_lds) for proj/fc1/fc2
// into the dead K+V LDS region -> per-block weight L2 traffic 720->220 KB.
typedef __attribute__((ext_vector_type(8))) short short8;  // 8 bf16 = one A/B frag
typedef __attribute__((ext_vector_type(4))) float f32x4;   // C/D frag

constexpr int HW = 56;

// ---- LDS pool (bf16 elements). Frag-read bases 16B-aligned. ----
constexpr int SR    = 104;             // row stride for [64][96] token-major buffers
constexpr int SVT   = 200;             // row stride for vT [32][3*64]
constexpr int OFF_X = 0;               // [64][SR]: xln -> P (own row) -> fc1 h-chunk (own row)
constexpr int OFF_Q = 64 * SR;         // [64][SR]: q -> attn-out (own row) -> yn (own row)
constexpr int OFF_K = 2 * 64 * SR;     // [64][SR]: k ; after attention: weight stage buffer
constexpr int OFF_V = 3 * 64 * SR;     // [32][SVT]: v^T ; part of stage buffer after attn
constexpr int POOLN = OFF_V + 32 * SVT;  // 26368 shorts = 52736 B -> 3 blocks/CU
// stage buffer = [OFF_K, POOLN) = 13056 shorts = 26112 B >= 18432 B chunk ✓

// ---- d_ws layout (bf16), frag-major: [(tile*3+s)*512 + lane*8 + j] ----
constexpr int WQKV  = 0;               // 18 tiles
constexpr int WPROJ = 27648;           // 6 tiles (18 sets = 18432 B, contiguous)
constexpr int WFC1  = 36864;           // 24 tiles (tile = 6*cn + nt; chunk cn = 18 sets)
constexpr int WFC2  = 73728;           // 24 tiles (tile = 6*cn + nt; chunk-major for staging)
constexpr int WTOT  = 110592;          // *2B = 221184 bytes

__device__ __forceinline__ ushort bfc(float f) {
  union { __hip_bfloat16 h; ushort u; } v;
  v.h = __float2bfloat16(f);
  return v.u;
}
__device__ __forceinline__ uint pk2(float a, float b) {
  union { __hip_bfloat162 h2; uint u; } v;
  v.h2 = __float22bfloat162_rn(make_float2(a, b));
  return v.u;
}
__device__ __forceinline__ void st4(short* p, float a, float b, float c, float d) {
  uint2 u; u.x = pk2(a, b); u.y = pk2(c, d);
  *(uint2*)p = u;
}
__device__ __forceinline__ short8 ldw8(const float* p) {
  float4 a = *(const float4*)p;
  float4 b = *(const float4*)(p + 4);
  short8 r;
  r[0] = (short)bfc(a.x); r[1] = (short)bfc(a.y); r[2] = (short)bfc(a.z); r[3] = (short)bfc(a.w);
  r[4] = (short)bfc(b.x); r[5] = (short)bfc(b.y); r[6] = (short)bfc(b.z); r[7] = (short)bfc(b.w);
  return r;
}
template<bool PRE>
__device__ __forceinline__ short8 wfrag(const short* wsb, int ts, int lane, const float* fsrc) {
  if constexpr (PRE) return *(const short8*)&wsb[(ts << 9) + lane * 8];
  else               return ldw8(fsrc);
}
// GELU sigmoid form: x * sigma(1.702 x)
__device__ __forceinline__ float gelu(float v) {
  return v / (1.0f + __expf(-1.702f * v));
}
// copy one 18432-byte weight chunk (18 frag-sets) global->LDS, coalesced, once per block
__device__ __forceinline__ void stage18k(const short* g0, short* l0, int wv, int lane) {
  #pragma unroll
  for (int i = 0; i < 4; ++i)
    __builtin_amdgcn_global_load_lds(
        (const unsigned int*)(g0 + i * 2048 + wv * 512 + lane * 8),
        (unsigned int*)(l0 + i * 2048 + wv * 512), 16, 0, 0);
  if (wv < 2)
    __builtin_amdgcn_global_load_lds(
        (const unsigned int*)(g0 + 8192 + wv * 512 + lane * 8),
        (unsigned int*)(l0 + 8192 + wv * 512), 16, 0, 0);
}

// one-shot weight conversion f32 -> bf16, frag-major
__global__ __launch_bounds__(256) void cvt_weights(
    const float* __restrict__ qkv_w, const float* __restrict__ proj_w,
    const float* __restrict__ fc1_w, const float* __restrict__ fc2_w,
    short* __restrict__ ws)
{
  int idx = blockIdx.x * 256 + threadIdx.x;
  if (idx >= WTOT) return;
  int j = idx & 7, lane = (idx >> 3) & 63;
  int cl = lane & 15;
  int g  = 8 * (lane >> 4) + j;
  float v;
  if (idx < WPROJ) {
    int ts = idx >> 9; int tile = ts / 3, s = ts - 3 * tile;
    v = qkv_w[(size_t)(16 * tile + cl) * 96 + 32 * s + g];
  } else if (idx < WFC1) {
    int ts = (idx - WPROJ) >> 9; int tile = ts / 3, s = ts - 3 * tile;
    v = proj_w[(size_t)(16 * tile + cl) * 96 + 32 * s + g];
  } else if (idx < WFC2) {
    int ts = (idx - WFC1) >> 9; int T = ts / 3, s = ts - 3 * T;
    int cn = T / 6, nt = T - 6 * cn;
    v = fc1_w[(size_t)(96 * cn + 16 * nt + cl) * 96 + 32 * s + g];
  } else {
    int ts = (idx - WFC2) >> 9; int T = ts / 3, s = ts - 3 * T;
    int cn = T / 6, nt = T - 6 * cn;   // chunk-major for staging
    v = fc2_w[(size_t)(16 * nt + cl) * 384 + 96 * cn + 32 * s + g];
  }
  ws[idx] = (short)bfc(v);
}

template<bool PRE>
__global__ __launch_bounds__(256, 3) void swin_mfma_kernel(
    const float* __restrict__ x,          // [B,3136,96]
    const float* __restrict__ attn_mask,  // [64,49,49]
    const int*   __restrict__ rel_index,  // [2401]
    const float* __restrict__ n1g, const float* __restrict__ n1b,
    const float* __restrict__ qkv_w, const float* __restrict__ qkv_b,
    const float* __restrict__ rel_tab,    // [169,3]
    const float* __restrict__ proj_w, const float* __restrict__ proj_b,
    const float* __restrict__ n2g, const float* __restrict__ n2b,
    const float* __restrict__ fc1_w, const float* __restrict__ fc1_b,
    const float* __restrict__ fc2_w, const float* __restrict__ fc2_b,
    const short* __restrict__ wsw,
    float* __restrict__ out)              // [B,3136,96]
{
  __shared__ alignas(16) short pool[POOLN];

  const int tid  = threadIdx.x;
  const int wv   = tid >> 6;          // wave id = token 16-strip owner
  const int lane = tid & 63;
  const int ln   = lane & 15;
  const int gq   = lane >> 4;
  const int bw   = blockIdx.x;
  const int b    = bw >> 6, widx = bw & 63;
  const int wr   = widx >> 3, wc = widx & 7;

  const f32x4 zf = {0.f, 0.f, 0.f, 0.f};
  const int qq = 16 * wv + ln;        // this thread's token row

  auto gbase = [&](int n) -> size_t {
    int i = n / 7, j = n - 7 * i;
    int h = wr * 7 + i + 3; if (h >= HW) h -= HW;   // roll(-3)
    int w = wc * 7 + j + 3; if (w >= HW) w -= HW;
    return ((size_t)b * (HW * HW) + (size_t)h * HW + w) * 96;
  };
  const size_t obase = gbase(qq < 49 ? qq : 48);

  // ---- stage 1: token-per-thread-column load + LN1 -> xln; raw x kept in VGPRs ----
  float xraw[6][4];
  {
    if (qq < 49) {
      const float* xr = x + obase;
      #pragma unroll
      for (int nt = 0; nt < 6; ++nt) {
        float4 v = *(const float4*)&xr[16 * nt + 4 * gq];
        xraw[nt][0] = v.x; xraw[nt][1] = v.y; xraw[nt][2] = v.z; xraw[nt][3] = v.w;
      }
    } else {
      #pragma unroll
      for (int nt = 0; nt < 6; ++nt)
        xraw[nt][0] = xraw[nt][1] = xraw[nt][2] = xraw[nt][3] = 0.f;
    }
    float s1 = 0.f, s2 = 0.f;
    #pragma unroll
    for (int nt = 0; nt < 6; ++nt)
      #pragma unroll
      for (int r = 0; r < 4; ++r) { s1 += xraw[nt][r]; s2 += xraw[nt][r] * xraw[nt][r]; }
    s1 += __shfl_xor(s1, 16, 64); s1 += __shfl_xor(s1, 32, 64);
    s2 += __shfl_xor(s2, 16, 64); s2 += __shfl_xor(s2, 32, 64);
    float mean = s1 * (1.f / 96.f);
    float inv  = rsqrtf(s2 * (1.f / 96.f) - mean * mean + 1e-5f);
    #pragma unroll
    for (int nt = 0; nt < 6; ++nt) {
      float4 g4 = *(const float4*)&n1g[16 * nt + 4 * gq];
      float4 b4 = *(const float4*)&n1b[16 * nt + 4 * gq];
      st4(&pool[OFF_X + qq * SR + 16 * nt + 4 * gq],
          (xraw[nt][0] - mean) * inv * g4.x + b4.x,
          (xraw[nt][1] - mean) * inv * g4.y + b4.y,
          (xraw[nt][2] - mean) * inv * g4.z + b4.z,
          (xraw[nt][3] - mean) * inv * g4.w + b4.w);
    }
  }
  __syncthreads();

  // ---- stage 2: QKV. Q/K channel-rows; V transposed token-rows. N-split across waves ----
  {
    short8 af[3][4];
    #pragma unroll
    for (int s = 0; s < 3; ++s)
      #pragma unroll
      for (int m = 0; m < 4; ++m)
        af[s][m] = *(const short8*)&pool[OFF_X + (16 * m + ln) * SR + 32 * s + 8 * gq];

    for (int t = wv; t < 18; t += 4) {
      short8 wf[3];
      #pragma unroll
      for (int s = 0; s < 3; ++s)
        wf[s] = wfrag<PRE>(wsw + WQKV, t * 3 + s, lane,
                           qkv_w + (size_t)(16 * t + ln) * 96 + 32 * s + 8 * gq);
      int which = t / 6;               // 0=q 1=k 2=v
      if (which == 2) {
        // V: D[token][chan] -> store transposed V^T[d][h*64+tok]
        int d  = 16 * (t - 12) + ln;
        float bv = qkv_b[192 + d];
        int dd = d & 31, hh = d >> 5;
        #pragma unroll
        for (int m = 0; m < 4; ++m) {
          f32x4 acc = zf;
          #pragma unroll
          for (int s = 0; s < 3; ++s)
            acc = __builtin_amdgcn_mfma_f32_16x16x32_bf16(af[s][m], wf[s], acc, 0, 0, 0);
          st4(&pool[OFF_V + dd * SVT + hh * 64 + 16 * m + 4 * gq],
              acc[0] + bv, acc[1] + bv, acc[2] + bv, acc[3] + bv);
        }
      } else {
        // Q/K: D[chan][token]; chans 16t+4gq..+3, token 16m+ln
        float4 b4 = *(const float4*)&qkv_b[16 * t + 4 * gq];
        #pragma unroll
        for (int m = 0; m < 4; ++m) {
          f32x4 acc = zf;
          #pragma unroll
          for (int s = 0; s < 3; ++s)
            acc = __builtin_amdgcn_mfma_f32_16x16x32_bf16(wf[s], af[s][m], acc, 0, 0, 0);
          int tok = 16 * m + ln;
          float v0 = acc[0] + b4.x, v1 = acc[1] + b4.y, v2 = acc[2] + b4.z, v3 = acc[3] + b4.w;
          if (which == 0) {
            const float sc_ = 0.17677669529663687f;
            st4(&pool[OFF_Q + tok * SR + 16 * t + 4 * gq], v0 * sc_, v1 * sc_, v2 * sc_, v3 * sc_);
          } else {
            st4(&pool[OFF_K + tok * SR + 16 * (t - 6) + 4 * gq], v0, v1, v2, v3);
          }
        }
      }
    }
  }
  __syncthreads();

  // ---- stage 3: attention (own-row P / attn-out; no barriers inside) ----
  int   relvv[4][4];
  float maskb[4][4];
  {
    int qc = qq < 49 ? qq : 48;
    #pragma unroll
    for (int nt = 0; nt < 4; ++nt)
      #pragma unroll
      for (int r = 0; r < 4; ++r) {
        int key = 16 * nt + 4 * gq + r;
        if (key < 49) {
          int qk = qc * 49 + key;
          relvv[nt][r] = rel_index[qk];
          maskb[nt][r] = attn_mask[(size_t)widx * 2401 + qk];
        } else {
          relvv[nt][r] = 0;
          maskb[nt][r] = -1e30f;
        }
      }
  }

  for (int h = 0; h < 3; ++h) {
    short8 bq = *(const short8*)&pool[OFF_Q + qq * SR + h * 32 + 8 * gq];
    f32x4 sc[4];
    #pragma unroll
    for (int nt = 0; nt < 4; ++nt) {
      short8 ak = *(const short8*)&pool[OFF_K + (16 * nt + ln) * SR + h * 32 + 8 * gq];
      sc[nt] = __builtin_amdgcn_mfma_f32_16x16x32_bf16(ak, bq, zf, 0, 0, 0);
    }
    float pv[4][4];
    float mx = -1e30f;
    #pragma unroll
    for (int nt = 0; nt < 4; ++nt)
      #pragma unroll
      for (int r = 0; r < 4; ++r) {
        float v = sc[nt][r] + rel_tab[relvv[nt][r] * 3 + h] + maskb[nt][r];
        pv[nt][r] = v;
        mx = fmaxf(mx, v);
      }
    mx = fmaxf(mx, __shfl_xor(mx, 16, 64));
    mx = fmaxf(mx, __shfl_xor(mx, 32, 64));
    float sum = 0.f;
    #pragma unroll
    for (int nt = 0; nt < 4; ++nt)
      #pragma unroll
      for (int r = 0; r < 4; ++r) { pv[nt][r] = __expf(pv[nt][r] - mx); sum += pv[nt][r]; }
    sum += __shfl_xor(sum, 16, 64);
    sum += __shfl_xor(sum, 32, 64);
    float inv = 1.f / sum;
    #pragma unroll
    for (int nt = 0; nt < 4; ++nt)
      st4(&pool[OFF_X + qq * SR + 16 * nt + 4 * gq],
          pv[nt][0] * inv, pv[nt][1] * inv, pv[nt][2] * inv, pv[nt][3] * inv);

    short8 bp0 = *(const short8*)&pool[OFF_X + qq * SR + 8 * gq];
    short8 bp1 = *(const short8*)&pool[OFF_X + qq * SR + 32 + 8 * gq];
    #pragma unroll
    for (int dt = 0; dt < 2; ++dt) {
      short8 av0 = *(const short8*)&pool[OFF_V + (16 * dt + ln) * SVT + h * 64 + 8 * gq];
      short8 av1 = *(const short8*)&pool[OFF_V + (16 * dt + ln) * SVT + h * 64 + 32 + 8 * gq];
      f32x4 o = __builtin_amdgcn_mfma_f32_16x16x32_bf16(av0, bp0, zf, 0, 0, 0);
      o = __builtin_amdgcn_mfma_f32_16x16x32_bf16(av1, bp1, o, 0, 0, 0);
      st4(&pool[OFF_Q + qq * SR + h * 32 + 16 * dt + 4 * gq], o[0], o[1], o[2], o[3]);
    }
  }

  // ---- stage 4: proj (weights staged in dead K/V region) + residual + LN2 ----
  short8 ao[3];
  #pragma unroll
  for (int s = 0; s < 3; ++s)
    ao[s] = *(const short8*)&pool[OFF_Q + qq * SR + 32 * s + 8 * gq];
  __syncthreads();   // all waves done with K/V and attn-out reads
  if constexpr (PRE) stage18k(wsw + WPROJ, (short*)&pool[OFF_K], wv, lane);
  __syncthreads();

  float y[6][4];
  {
    #pragma unroll
    for (int nt = 0; nt < 6; ++nt) {
      f32x4 acc = zf;
      #pragma unroll
      for (int s = 0; s < 3; ++s) {
        short8 wfr = PRE ? *(const short8*)&pool[OFF_K + (nt * 3 + s) * 512 + lane * 8]
                         : ldw8(proj_w + (size_t)(16 * nt + ln) * 96 + 32 * s + 8 * gq);
        acc = __builtin_amdgcn_mfma_f32_16x16x32_bf16(wfr, ao[s], acc, 0, 0, 0);
      }
      float4 pb = *(const float4*)&proj_b[16 * nt + 4 * gq];
      y[nt][0] = acc[0] + pb.x + xraw[nt][0];
      y[nt][1] = acc[1] + pb.y + xraw[nt][1];
      y[nt][2] = acc[2] + pb.z + xraw[nt][2];
      y[nt][3] = acc[3] + pb.w + xraw[nt][3];
    }
    float s1 = 0.f, s2 = 0.f;
    #pragma unroll
    for (int nt = 0; nt < 6; ++nt)
      #pragma unroll
      for (int r = 0; r < 4; ++r) { s1 += y[nt][r]; s2 += y[nt][r] * y[nt][r]; }
    s1 += __shfl_xor(s1, 16, 64); s1 += __shfl_xor(s1, 32, 64);
    s2 += __shfl_xor(s2, 16, 64); s2 += __shfl_xor(s2, 32, 64);
    float mean = s1 * (1.f / 96.f);
    float inv  = rsqrtf(s2 * (1.f / 96.f) - mean * mean + 1e-5f);
    #pragma unroll
    for (int nt = 0; nt < 6; ++nt) {
      float4 g4 = *(const float4*)&n2g[16 * nt + 4 * gq];
      float4 b4 = *(const float4*)&n2b[16 * nt + 4 * gq];
      st4(&pool[OFF_Q + qq * SR + 16 * nt + 4 * gq],
          (y[nt][0] - mean) * inv * g4.x + b4.x,
          (y[nt][1] - mean) * inv * g4.y + b4.y,
          (y[nt][2] - mean) * inv * g4.z + b4.z,
          (y[nt][3] - mean) * inv * g4.w + b4.w);
    }
  }

  // ---- stage 5: MLP, 4 chunks of 96 hidden; weights staged per chunk ----
  f32x4 accO[6] = {zf, zf, zf, zf, zf, zf};
  short8 ay[3];
  #pragma unroll
  for (int s = 0; s < 3; ++s)
    ay[s] = *(const short8*)&pool[OFF_Q + qq * SR + 32 * s + 8 * gq];

  for (int cn = 0; cn < 4; ++cn) {
    __syncthreads();   // all waves done reading previous chunk (or proj)
    if constexpr (PRE) stage18k(wsw + WFC1 + 9216 * cn, (short*)&pool[OFF_K], wv, lane);
    __syncthreads();
    #pragma unroll
    for (int nt = 0; nt < 6; ++nt) {
      f32x4 acc = zf;
      #pragma unroll
      for (int s = 0; s < 3; ++s) {
        short8 wfr = PRE ? *(const short8*)&pool[OFF_K + (nt * 3 + s) * 512 + lane * 8]
                         : ldw8(fc1_w + (size_t)(96 * cn + 16 * nt + ln) * 96 + 32 * s + 8 * gq);
        acc = __builtin_amdgcn_mfma_f32_16x16x32_bf16(wfr, ay[s], acc, 0, 0, 0);
      }
      float4 b1 = *(const float4*)&fc1_b[96 * cn + 16 * nt + 4 * gq];
      st4(&pool[OFF_X + qq * SR + 16 * nt + 4 * gq],
          gelu(acc[0] + b1.x), gelu(acc[1] + b1.y),
          gelu(acc[2] + b1.z), gelu(acc[3] + b1.w));
    }
    short8 ah[3];
    #pragma unroll
    for (int s = 0; s < 3; ++s)
      ah[s] = *(const short8*)&pool[OFF_X + qq * SR + 32 * s + 8 * gq];
    __syncthreads();   // all waves done reading fc1 chunk
    if constexpr (PRE) stage18k(wsw + WFC2 + 9216 * cn, (short*)&pool[OFF_K], wv, lane);
    __syncthreads();
    #pragma unroll
    for (int nt = 0; nt < 6; ++nt) {
      #pragma unroll
      for (int s = 0; s < 3; ++s) {
        short8 wfr = PRE ? *(const short8*)&pool[OFF_K + (nt * 3 + s) * 512 + lane * 8]
                         : ldw8(fc2_w + (size_t)(16 * nt + ln) * 384 + 96 * cn + 32 * s + 8 * gq);
        accO[nt] = __builtin_amdgcn_mfma_f32_16x16x32_bf16(wfr, ah[s], accO[nt], 0, 0, 0);
      }
    }
  }

  // ---- stage 6: out = y + mlp + fc2_b (float4 stores) ----
  if (qq < 49) {
    float* dst = out + obase;
    #pragma unroll
    for (int nt = 0; nt < 6; ++nt) {
      float4 fb = *(const float4*)&fc2_b[16 * nt + 4 * gq];
      float4 v;
      v.x = y[nt][0] + accO[nt][0] + fb.x;
      v.y = y[nt][1] + accO[nt][1] + fb.y;
      v.z = y[nt][2] + accO[nt][2] + fb.z;
      v.w = y[nt][3] + accO[nt][3] + fb.w;
      *(float4*)&dst[16 * nt + 4 * gq] = v;
    }
  }
}

extern "C" void kernel_launch(void* const* d_in, const int* in_sizes, int n_in,
                              void* d_out, int out_size, void* d_ws, size_t ws_size,
                              hipStream_t stream) {
  const float* x         = (const float*)d_in[0];
  const float* attn_mask = (const float*)d_in[1];
  const int*   rel_index = (const int*)  d_in[2];
  const float* n1g       = (const float*)d_in[3];
  const float* n1b       = (const float*)d_in[4];
  const float* qkv_w     = (const float*)d_in[5];
  const float* qkv_b     = (const float*)d_in[6];
  const float* rel_tab   = (const float*)d_in[7];
  const float* proj_w    = (const float*)d_in[8];
  const float* proj_b    = (const float*)d_in[9];
  const float* n2g       = (const float*)d_in[10];
  const float* n2b       = (const float*)d_in[11];
  const float* fc1_w     = (const float*)d_in[12];
  const float* fc1_b     = (const float*)d_in[13];
  const float* fc2_w     = (const float*)d_in[14];
  const float* fc2_b     = (const float*)d_in[15];
  float* out = (float*)d_out;

  const int B = in_sizes[0] / (HW * HW * 96);
  const bool pre = ws_size >= (size_t)WTOT * 2;

  if (pre) {
    short* ws = (short*)d_ws;
    cvt_weights<<<(WTOT + 255) / 256, 256, 0, stream>>>(qkv_w, proj_w, fc1_w, fc2_w, ws);
    swin_mfma_kernel<true><<<B * 64, 256, 0, stream>>>(
        x, attn_mask, rel_index, n1g, n1b, qkv_w, qkv_b, rel_tab, proj_w, proj_b,
        n2g, n2b, fc1_w, fc1_b, fc2_w, fc2_b, (const short*)ws, out);
  } else {
    swin_mfma_kernel<false><<<B * 64, 256, 0, stream>>>(
        x, attn_mask, rel_index, n1g, n1b, qkv_w, qkv_b, rel_tab, proj_w, proj_b,
        n2g, n2b, fc1_w, fc1_b, fc2_w, fc2_b, (const short*)nullptr, out);
  }
}